// Round 7
// baseline (282.051 us; speedup 1.0000x reference)
//
#include <hip/hip_runtime.h>
#include <stdint.h>

typedef __bf16 bf16;
typedef __attribute__((ext_vector_type(8))) __bf16 bf16x8;
typedef __attribute__((ext_vector_type(4))) float f32x4;

#define SEQ   2048
#define DM    1024
#define NH    16
#define HD    64
#define MROWS 4096   // B*L

__device__ __forceinline__ void glds16(const bf16* g, bf16* l) {
  __builtin_amdgcn_global_load_lds(
      (__attribute__((address_space(1))) unsigned int*)(g),
      (__attribute__((address_space(3))) unsigned int*)(l),
      16, 0, 0);
}

static __device__ __forceinline__ bf16x8 cvt_f32x8(const float* __restrict__ p) {
  const f32x4 a = *(const f32x4*)p;
  const f32x4 b = *(const f32x4*)(p + 4);
  bf16x8 r;
  r[0] = (bf16)a[0]; r[1] = (bf16)a[1]; r[2] = (bf16)a[2]; r[3] = (bf16)a[3];
  r[4] = (bf16)b[0]; r[5] = (bf16)b[1]; r[6] = (bf16)b[2]; r[7] = (bf16)b[3];
  return r;
}

// fp32 -> bf16 weight conversion (4 x [1024,1024])
__global__ void conv4(const float* __restrict__ s0, const float* __restrict__ s1,
                      const float* __restrict__ s2, const float* __restrict__ s3,
                      bf16* __restrict__ d0, bf16* __restrict__ d1,
                      bf16* __restrict__ d2, bf16* __restrict__ d3) {
  const float* s = blockIdx.z == 0 ? s0 : (blockIdx.z == 1 ? s1 : (blockIdx.z == 2 ? s2 : s3));
  bf16* d = blockIdx.z == 0 ? d0 : (blockIdx.z == 1 ? d1 : (blockIdx.z == 2 ? d2 : d3));
  const size_t i = ((size_t)blockIdx.x * 256 + threadIdx.x) * 8;
  *(bf16x8*)(d + i) = cvt_f32x8(s + i);
}

// ---------------------------------------------------------------------------
// Fused QKV projection, one dispatch, grid (8,32,3), double-buffered K-loop.
// z=0: Qh = (q @ Wq^T + bq)*0.125, head layout [B,H,L,64]
// z=1: Kh =  k @ Wk^T + bk,        head layout
// z=2: Vt = (Wv @ v^T + bv), store [B,H,64,SEQ] with within-128 key
//      permutation key' = (l&15)*8 + ((l>>4)&7)
// One operand per z is fp32 (cvt-staged via VALU+ds_write), the other bf16
// (async glds16). XOR chunk swizzle (source chunk c ^ (row&7), linear LDS).
// ---------------------------------------------------------------------------
__global__ __launch_bounds__(256, 2) void proj_qkv(
    const float* __restrict__ qf, const float* __restrict__ kf, const float* __restrict__ vf,
    const bf16* __restrict__ Wqb, const bf16* __restrict__ Wkb, const bf16* __restrict__ Wvb,
    const float* __restrict__ bq, const float* __restrict__ bk, const float* __restrict__ bv,
    bf16* __restrict__ Qh, bf16* __restrict__ Kh, bf16* __restrict__ Vt)
{
  __shared__ __align__(16) bf16 sA[2][128 * 64];
  __shared__ __align__(16) bf16 sB[2][128 * 64];

  const int z = blockIdx.z;
  // A operand (m rows): z<2 -> fp32 activation; z==2 -> bf16 Wv
  // B operand (n rows): z<2 -> bf16 weight;     z==2 -> fp32 v
  const float* Af = (z == 0) ? qf : kf;
  const bf16*  Ab = Wvb;
  const bf16*  Bb = (z == 0) ? Wqb : Wkb;
  const float* Bf = vf;
  const float* Bv = (z == 0) ? bq : ((z == 1) ? bk : bv);
  const bool a_f32 = (z < 2);

  const int tid  = threadIdx.x;
  const int lane = tid & 63;
  const int wv   = tid >> 6;
  const int quad = lane >> 4;
  const int colx = lane & 15;
  const int m0 = (z == 2) ? (int)blockIdx.x * 128 : (int)blockIdx.y * 128;
  const int n0 = (z == 2) ? (int)blockIdx.y * 128 : (int)blockIdx.x * 128;
  const int rm = (wv >> 1) * 64;
  const int rn = (wv & 1) * 64;

  // per-thread staging coordinates (4 chunks per tile)
  int srow[4], schunk[4];
#pragma unroll
  for (int i = 0; i < 4; ++i) {
    const int f = i * 256 + tid;
    srow[i] = f >> 3;
    schunk[i] = (f & 7) ^ (srow[i] & 7);
  }

  f32x4 acc[4][4];
#pragma unroll
  for (int mi = 0; mi < 4; ++mi)
#pragma unroll
    for (int ni = 0; ni < 4; ++ni) {
      f32x4 zz = {0.f, 0.f, 0.f, 0.f};
      acc[mi][ni] = zz;
    }

  // stage tile kt into buffer bu
  auto stage = [&](int kt, int bu) {
    const int k0 = kt * 64;
#pragma unroll
    for (int i = 0; i < 4; ++i) {
      const int f = i * 256 + tid;
      const int row = srow[i], cc = schunk[i];
      if (a_f32) {
        *(bf16x8*)(&sA[bu][f * 8]) = cvt_f32x8(Af + (size_t)(m0 + row) * DM + k0 + cc * 8);
        glds16(Bb + (size_t)(n0 + row) * DM + k0 + cc * 8, &sB[bu][f * 8]);
      } else {
        glds16(Ab + (size_t)(m0 + row) * DM + k0 + cc * 8, &sA[bu][f * 8]);
        *(bf16x8*)(&sB[bu][f * 8]) = cvt_f32x8(Bf + (size_t)(n0 + row) * DM + k0 + cc * 8);
      }
    }
  };

  stage(0, 0);
  for (int kt = 0; kt < 16; ++kt) {
    const int bu = kt & 1;
    __syncthreads();                      // tile kt staged & visible
    if (kt < 15) stage(kt + 1, bu ^ 1);   // prefetch next tile (hidden by compute)

    bf16x8 af[4][2], bfr[4][2];
#pragma unroll
    for (int t4 = 0; t4 < 4; ++t4) {
#pragma unroll
      for (int ks = 0; ks < 2; ++ks) {
        const int ra = rm + t4 * 16 + colx;
        af[t4][ks] = *(const bf16x8*)(&sA[bu][ra * 64 + (((ks * 4 + quad) ^ (ra & 7)) * 8)]);
        const int rb = rn + t4 * 16 + colx;
        bfr[t4][ks] = *(const bf16x8*)(&sB[bu][rb * 64 + (((ks * 4 + quad) ^ (rb & 7)) * 8)]);
      }
    }
#pragma unroll
    for (int mi = 0; mi < 4; ++mi)
#pragma unroll
      for (int ni = 0; ni < 4; ++ni) {
        acc[mi][ni] = __builtin_amdgcn_mfma_f32_16x16x32_bf16(af[mi][0], bfr[ni][0], acc[mi][ni], 0, 0, 0);
        acc[mi][ni] = __builtin_amdgcn_mfma_f32_16x16x32_bf16(af[mi][1], bfr[ni][1], acc[mi][ni], 0, 0, 0);
      }
  }

  // epilogue. C/D: row = quad*4+r, col = colx (m89).
  if (z == 2) {
    // Vt permuted store; bias indexed by m (= Wv row)
#pragma unroll
    for (int mi = 0; mi < 4; ++mi) {
#pragma unroll
      for (int r = 0; r < 4; ++r) {
        const int m = m0 + rm + mi * 16 + quad * 4 + r;
        const float bias = Bv[m];
        const int hh = m >> 6, d = m & 63;
#pragma unroll
        for (int ni = 0; ni < 4; ++ni) {
          const int n = n0 + rn + ni * 16 + colx;   // v row = b*2048+l
          const int b = n >> 11, l = n & 2047;
          const int lb = l >> 7, li = l & 127;
          const int perm = (li & 15) * 8 + ((li >> 4) & 7);
          Vt[(((size_t)(b * NH + hh) * HD + d) * SEQ) + lb * 128 + perm] =
              (bf16)(acc[mi][ni][r] + bias);
        }
      }
    }
  } else {
    bf16* Out = (z == 0) ? Qh : Kh;
    const float scale = (z == 0) ? 0.125f : 1.0f;
#pragma unroll
    for (int ni = 0; ni < 4; ++ni) {
      const int n = n0 + rn + ni * 16 + colx;
      const float bias = Bv[n];
#pragma unroll
      for (int mi = 0; mi < 4; ++mi) {
#pragma unroll
        for (int r = 0; r < 4; ++r) {
          const int m = m0 + rm + mi * 16 + quad * 4 + r;
          const float v = (acc[mi][ni][r] + bias) * scale;
          const int b = m >> 11, l = m & 2047, hh = n >> 6, d = n & 63;
          Out[((size_t)(b * NH + hh) * SEQ + l) * HD + d] = (bf16)v;
        }
      }
    }
  }
}

// ---------------------------------------------------------------------------
// Output projection: out = At[4096,1024] @ Wo^T + bo (fp32 store).
// Both operands bf16 via glds16; double-buffered like proj_qkv.
// ---------------------------------------------------------------------------
__global__ __launch_bounds__(256, 2) void proj_out(
    const bf16* __restrict__ At, const bf16* __restrict__ Wob,
    const float* __restrict__ bo, float* __restrict__ Out)
{
  __shared__ __align__(16) bf16 sA[2][128 * 64];
  __shared__ __align__(16) bf16 sB[2][128 * 64];

  const int tid  = threadIdx.x;
  const int lane = tid & 63;
  const int wv   = tid >> 6;
  const int quad = lane >> 4;
  const int colx = lane & 15;
  const int m0 = blockIdx.y * 128;
  const int n0 = blockIdx.x * 128;
  const int rm = (wv >> 1) * 64;
  const int rn = (wv & 1) * 64;

  f32x4 acc[4][4];
#pragma unroll
  for (int mi = 0; mi < 4; ++mi)
#pragma unroll
    for (int ni = 0; ni < 4; ++ni) {
      f32x4 zz = {0.f, 0.f, 0.f, 0.f};
      acc[mi][ni] = zz;
    }

  auto stage = [&](int kt, int bu) {
    const int k0 = kt * 64;
#pragma unroll
    for (int i = 0; i < 4; ++i) {
      const int f = i * 256 + tid;
      const int row = f >> 3;
      const int cc = (f & 7) ^ (row & 7);
      glds16(At  + (size_t)(m0 + row) * DM + k0 + cc * 8, &sA[bu][f * 8]);
      glds16(Wob + (size_t)(n0 + row) * DM + k0 + cc * 8, &sB[bu][f * 8]);
    }
  };

  stage(0, 0);
  for (int kt = 0; kt < 16; ++kt) {
    const int bu = kt & 1;
    __syncthreads();
    if (kt < 15) stage(kt + 1, bu ^ 1);

    bf16x8 af[4][2], bfr[4][2];
#pragma unroll
    for (int t4 = 0; t4 < 4; ++t4) {
#pragma unroll
      for (int ks = 0; ks < 2; ++ks) {
        const int ra = rm + t4 * 16 + colx;
        af[t4][ks] = *(const bf16x8*)(&sA[bu][ra * 64 + (((ks * 4 + quad) ^ (ra & 7)) * 8)]);
        const int rb = rn + t4 * 16 + colx;
        bfr[t4][ks] = *(const bf16x8*)(&sB[bu][rb * 64 + (((ks * 4 + quad) ^ (rb & 7)) * 8)]);
      }
    }
#pragma unroll
    for (int mi = 0; mi < 4; ++mi)
#pragma unroll
      for (int ni = 0; ni < 4; ++ni) {
        acc[mi][ni] = __builtin_amdgcn_mfma_f32_16x16x32_bf16(af[mi][0], bfr[ni][0], acc[mi][ni], 0, 0, 0);
        acc[mi][ni] = __builtin_amdgcn_mfma_f32_16x16x32_bf16(af[mi][1], bfr[ni][1], acc[mi][ni], 0, 0, 0);
      }
  }

#pragma unroll
  for (int ni = 0; ni < 4; ++ni) {
    const int n = n0 + rn + ni * 16 + colx;
    const float bias = bo[n];
#pragma unroll
    for (int mi = 0; mi < 4; ++mi) {
#pragma unroll
      for (int r = 0; r < 4; ++r) {
        const int m = m0 + rm + mi * 16 + quad * 4 + r;
        Out[(size_t)m * DM + n] = acc[mi][ni][r] + bias;
      }
    }
  }
}

// ---------------------------------------------------------------------------
// Flash attention (unchanged from R6 — verified, 0 bank conflicts).
// ---------------------------------------------------------------------------
__global__ __launch_bounds__(256, 2) void attn_kernel(
    const bf16* __restrict__ Qh, const bf16* __restrict__ Kh, const bf16* __restrict__ Vt,
    const int* __restrict__ mask, bf16* __restrict__ At)
{
  __shared__ __align__(16) bf16 sK[128 * 64];
  __shared__ __align__(16) bf16 sVt[80 * 128];
  __shared__ __align__(16) bf16 sP[4][32 * 128];

  const int tid  = threadIdx.x;
  const int lane = tid & 63;
  const int wv   = tid >> 6;
  const int quad = lane >> 4;
  const int colx = lane & 15;
  const int bh = blockIdx.y;
  const int b  = bh >> 4;
  const int h  = bh & 15;
  const int q0 = blockIdx.x * 128;
  const size_t base  = (size_t)bh * SEQ * HD;
  const size_t baseV = (size_t)bh * HD * SEQ;

  {
    const int row = 64 + (tid >> 4);
    const float val = (row == 64) ? 1.0f : 0.0f;
    bf16x8 vv;
#pragma unroll
    for (int j = 0; j < 8; ++j) vv[j] = (bf16)val;
    *(bf16x8*)(sVt + row * 128 + (tid & 15) * 8) = vv;
  }

  bf16x8 qf[2][2];
#pragma unroll
  for (int half = 0; half < 2; ++half) {
    const int qrow = q0 + wv * 32 + half * 16 + colx;
    qf[half][0] = *(const bf16x8*)(Qh + base + (size_t)qrow * HD + quad * 8);
    qf[half][1] = *(const bf16x8*)(Qh + base + (size_t)qrow * HD + 32 + quad * 8);
  }

  f32x4 o[2][5];
#pragma unroll
  for (int half = 0; half < 2; ++half)
#pragma unroll
    for (int dt = 0; dt < 5; ++dt) {
      f32x4 zz = {0.f, 0.f, 0.f, 0.f};
      o[half][dt] = zz;
    }
  bf16* sPw = &sP[wv][0];

  for (int kc = 0; kc < 16; ++kc) {
    const int key0 = kc * 128;
    __syncthreads();
#pragma unroll
    for (int i = 0; i < 4; ++i) {
      const int f = i * 256 + tid;
      const int kr = f >> 3;
      const int ck = (f & 7) ^ (kr & 7);
      glds16(Kh + base + (size_t)(key0 + kr) * HD + ck * 8, sK + f * 8);
      const int dr = f >> 4;
      const int cv = (f & 15) ^ (dr & 15);
      glds16(Vt + baseV + (size_t)dr * SEQ + key0 + cv * 8, sVt + f * 8);
    }
    float mreg[8];
#pragma unroll
    for (int nt = 0; nt < 8; ++nt)
      mreg[nt] = (mask[b * SEQ + key0 + nt * 16 + colx] ? -1e30f : 0.0f) - 16.0f;
    __syncthreads();

#pragma unroll
    for (int half = 0; half < 2; ++half) {
      f32x4 s8[8];
#pragma unroll
      for (int nt = 0; nt < 8; ++nt) {
        f32x4 s = {0.f, 0.f, 0.f, 0.f};
        const int krow = nt * 16 + colx;
#pragma unroll
        for (int ks = 0; ks < 2; ++ks) {
          const bf16x8 kf = *(const bf16x8*)(sK + krow * 64 + (((ks * 4 + quad) ^ (krow & 7)) * 8));
          s = __builtin_amdgcn_mfma_f32_16x16x32_bf16(qf[half][ks], kf, s, 0, 0, 0);
        }
        s8[nt] = s;
      }
#pragma unroll
      for (int r = 0; r < 4; ++r) {
        bf16x8 pk;
#pragma unroll
        for (int nt = 0; nt < 8; ++nt)
          pk[nt] = (bf16)__expf(s8[nt][r] + mreg[nt]);
        const int row = half * 16 + quad * 4 + r;
        *(bf16x8*)(sPw + row * 128 + ((colx ^ (row & 15)) * 8)) = pk;
      }
    }

#pragma unroll
    for (int ks = 0; ks < 4; ++ks) {
      const int ch = ((ks * 4 + quad) ^ colx) * 8;
      const bf16x8 pf0 = *(const bf16x8*)(sPw + colx * 128 + ch);
      const bf16x8 pf1 = *(const bf16x8*)(sPw + (16 + colx) * 128 + ch);
#pragma unroll
      for (int dt = 0; dt < 5; ++dt) {
        const int drow = (dt < 4) ? (dt * 16 + colx) : (64 + colx);
        const bf16x8 vf = *(const bf16x8*)(sVt + drow * 128 + ch);
        o[0][dt] = __builtin_amdgcn_mfma_f32_16x16x32_bf16(pf0, vf, o[0][dt], 0, 0, 0);
        o[1][dt] = __builtin_amdgcn_mfma_f32_16x16x32_bf16(pf1, vf, o[1][dt], 0, 0, 0);
      }
    }
  }

#pragma unroll
  for (int half = 0; half < 2; ++half) {
#pragma unroll
    for (int r = 0; r < 4; ++r) {
      const float lsum = __shfl(o[half][4][r], (lane & 48));
      const float inv = 1.0f / lsum;
      const int q = q0 + wv * 32 + half * 16 + quad * 4 + r;
#pragma unroll
      for (int dt = 0; dt < 4; ++dt) {
        At[((size_t)(b * SEQ + q)) * DM + h * HD + dt * 16 + colx] =
            (bf16)(o[half][dt][r] * inv);
      }
    }
  }
}

extern "C" void kernel_launch(void* const* d_in, const int* in_sizes, int n_in,
                              void* d_out, int out_size, void* d_ws, size_t ws_size,
                              hipStream_t stream) {
  (void)in_sizes; (void)n_in; (void)out_size; (void)ws_size;
  const float* q    = (const float*)d_in[0];
  const float* k    = (const float*)d_in[1];
  const float* v    = (const float*)d_in[2];
  const int*   mask = (const int*)d_in[3];
  const float* Wq   = (const float*)d_in[4];
  const float* bq   = (const float*)d_in[5];
  const float* Wk   = (const float*)d_in[6];
  const float* bk   = (const float*)d_in[7];
  const float* Wv   = (const float*)d_in[8];
  const float* bv   = (const float*)d_in[9];
  const float* Wo   = (const float*)d_in[10];
  const float* bo   = (const float*)d_in[11];
  float* out = (float*)d_out;

  const size_t T = (size_t)MROWS * DM;   // 4,194,304
  const size_t WT = (size_t)DM * DM;     // 1,048,576
  bf16* ws  = (bf16*)d_ws;
  bf16* Wqb = ws;
  bf16* Wkb = Wqb + WT;
  bf16* Wvb = Wkb + WT;
  bf16* Wob = Wvb + WT;
  bf16* Qh  = Wob + WT;
  bf16* Kh  = Qh + T;
  bf16* Vt  = Kh + T;
  bf16* At  = Vt + T;

  dim3 blk(256);
  conv4<<<dim3(512, 1, 4), blk, 0, stream>>>(Wq, Wk, Wv, Wo, Wqb, Wkb, Wvb, Wob);
  proj_qkv<<<dim3(8, 32, 3), blk, 0, stream>>>(q, k, v, Wqb, Wkb, Wvb, bq, bk, bv,
                                               Qh, Kh, Vt);
  attn_kernel<<<dim3(16, 32), blk, 0, stream>>>(Qh, Kh, Vt, mask, At);
  proj_out<<<dim3(8, 32), blk, 0, stream>>>(At, Wob, bo, out);
}

// Round 8
// 212.324 us; speedup vs baseline: 1.3284x; 1.3284x over previous
//
#include <hip/hip_runtime.h>
#include <stdint.h>

typedef __bf16 bf16;
typedef __attribute__((ext_vector_type(8))) __bf16 bf16x8;
typedef __attribute__((ext_vector_type(4))) float f32x4;

#define SEQ   2048
#define DM    1024
#define NH    16
#define HD    64
#define MROWS 4096   // B*L

__device__ __forceinline__ void glds16(const bf16* g, bf16* l) {
  __builtin_amdgcn_global_load_lds(
      (__attribute__((address_space(1))) unsigned int*)(g),
      (__attribute__((address_space(3))) unsigned int*)(l),
      16, 0, 0);
}

static __device__ __forceinline__ bf16x8 cvt_f32x8(const float* __restrict__ p) {
  const f32x4 a = *(const f32x4*)p;
  const f32x4 b = *(const f32x4*)(p + 4);
  bf16x8 r;
  r[0] = (bf16)a[0]; r[1] = (bf16)a[1]; r[2] = (bf16)a[2]; r[3] = (bf16)a[3];
  r[4] = (bf16)b[0]; r[5] = (bf16)b[1]; r[6] = (bf16)b[2]; r[7] = (bf16)b[3];
  return r;
}

// ---------------------------------------------------------------------------
// One-pass fp32->bf16 conversion of all 7 tensors (q,k,v,Wq,Wk,Wv,Wo).
// 2,097,152 chunks of 8 elements; boundaries block-uniform except at edges.
// ---------------------------------------------------------------------------
__global__ void conv_all(
    const float* __restrict__ q, const float* __restrict__ k, const float* __restrict__ v,
    const float* __restrict__ wq, const float* __restrict__ wk,
    const float* __restrict__ wv, const float* __restrict__ wo,
    bf16* __restrict__ dq, bf16* __restrict__ dk, bf16* __restrict__ dv,
    bf16* __restrict__ dwq, bf16* __restrict__ dwk, bf16* __restrict__ dwv,
    bf16* __restrict__ dwo)
{
  const size_t c = (size_t)blockIdx.x * 256 + threadIdx.x;
  const float* s; bf16* d; size_t off;
  if (c < 524288)        { s = q;  d = dq;  off = c; }
  else if (c < 1048576)  { s = k;  d = dk;  off = c - 524288; }
  else if (c < 1572864)  { s = v;  d = dv;  off = c - 1048576; }
  else if (c < 1703936)  { s = wq; d = dwq; off = c - 1572864; }
  else if (c < 1835008)  { s = wk; d = dwk; off = c - 1703936; }
  else if (c < 1966080)  { s = wv; d = dwv; off = c - 1835008; }
  else                   { s = wo; d = dwo; off = c - 1966080; }
  *(bf16x8*)(d + off * 8) = cvt_f32x8(s + off * 8);
}

// ---------------------------------------------------------------------------
// Fused QKV projection, all-bf16, single-buffered (32 KB LDS, 4 blocks/CU).
// z=0: Qh = (q@Wq^T+bq)*0.125 head layout; z=1: Kh; z=2: Vt = Wv@v^T+bv,
// [B,H,64,SEQ] with key' = (l&15)*8+((l>>4)&7) permutation.
// XCD-aware remap: o = bx + 8*by, XCD = o&7 (round-robin heuristic). The
// reuse-dim (activation) tile = (o&7)*4 + ((o>>3)&3) -> each XCD owns 4
// contiguous activation slices (1 MB) x all weights (2 MB) -> fits 4 MB L2.
// ---------------------------------------------------------------------------
__global__ __launch_bounds__(256, 4) void proj_qkv(
    const bf16* __restrict__ qb, const bf16* __restrict__ kb, const bf16* __restrict__ vb,
    const bf16* __restrict__ Wqb, const bf16* __restrict__ Wkb, const bf16* __restrict__ Wvb,
    const float* __restrict__ bq, const float* __restrict__ bk, const float* __restrict__ bv,
    bf16* __restrict__ Qh, bf16* __restrict__ Kh, bf16* __restrict__ Vt)
{
  __shared__ __align__(16) bf16 sA[128 * 64];
  __shared__ __align__(16) bf16 sB[128 * 64];

  const int z = blockIdx.z;
  const int o = (int)blockIdx.x + 8 * (int)blockIdx.y;
  const int rt = (o & 7) * 4 + ((o >> 3) & 3);  // reuse-dim tile 0..31
  const int ot = o >> 5;                        // other tile 0..7

  const bf16 *A, *B;
  const float* Bv;
  int m0, n0;
  if (z == 0)      { A = qb;  B = Wqb; Bv = bq; m0 = rt * 128; n0 = ot * 128; }
  else if (z == 1) { A = kb;  B = Wkb; Bv = bk; m0 = rt * 128; n0 = ot * 128; }
  else             { A = Wvb; B = vb;  Bv = bv; m0 = ot * 128; n0 = rt * 128; }

  const int tid  = threadIdx.x;
  const int lane = tid & 63;
  const int wv   = tid >> 6;
  const int quad = lane >> 4;
  const int colx = lane & 15;
  const int rm = (wv >> 1) * 64;
  const int rn = (wv & 1) * 64;

  f32x4 acc[4][4];
#pragma unroll
  for (int mi = 0; mi < 4; ++mi)
#pragma unroll
    for (int ni = 0; ni < 4; ++ni) {
      f32x4 zz = {0.f, 0.f, 0.f, 0.f};
      acc[mi][ni] = zz;
    }

  for (int kt = 0; kt < 16; ++kt) {
    const int k0 = kt * 64;
    __syncthreads();
#pragma unroll
    for (int i = 0; i < 4; ++i) {
      const int f = i * 256 + tid;
      const int row = f >> 3;
      const int cc = (f & 7) ^ (row & 7);
      glds16(A + (size_t)(m0 + row) * DM + k0 + cc * 8, sA + f * 8);
      glds16(B + (size_t)(n0 + row) * DM + k0 + cc * 8, sB + f * 8);
    }
    __syncthreads();

    bf16x8 af[4][2], bfr[4][2];
#pragma unroll
    for (int t4 = 0; t4 < 4; ++t4) {
#pragma unroll
      for (int ks = 0; ks < 2; ++ks) {
        const int ra = rm + t4 * 16 + colx;
        af[t4][ks] = *(const bf16x8*)(sA + ra * 64 + (((ks * 4 + quad) ^ (ra & 7)) * 8));
        const int rb = rn + t4 * 16 + colx;
        bfr[t4][ks] = *(const bf16x8*)(sB + rb * 64 + (((ks * 4 + quad) ^ (rb & 7)) * 8));
      }
    }
#pragma unroll
    for (int mi = 0; mi < 4; ++mi)
#pragma unroll
      for (int ni = 0; ni < 4; ++ni) {
        acc[mi][ni] = __builtin_amdgcn_mfma_f32_16x16x32_bf16(af[mi][0], bfr[ni][0], acc[mi][ni], 0, 0, 0);
        acc[mi][ni] = __builtin_amdgcn_mfma_f32_16x16x32_bf16(af[mi][1], bfr[ni][1], acc[mi][ni], 0, 0, 0);
      }
  }

  // epilogue. C/D: row = quad*4+r, col = colx (m89).
  if (z == 2) {
#pragma unroll
    for (int mi = 0; mi < 4; ++mi) {
#pragma unroll
      for (int r = 0; r < 4; ++r) {
        const int m = m0 + rm + mi * 16 + quad * 4 + r;  // Wv row = h*64+d
        const float bias = Bv[m];
        const int hh = m >> 6, d = m & 63;
#pragma unroll
        for (int ni = 0; ni < 4; ++ni) {
          const int n = n0 + rn + ni * 16 + colx;        // v row = b*2048+l
          const int b = n >> 11, l = n & 2047;
          const int lb = l >> 7, li = l & 127;
          const int perm = (li & 15) * 8 + ((li >> 4) & 7);
          Vt[(((size_t)(b * NH + hh) * HD + d) * SEQ) + lb * 128 + perm] =
              (bf16)(acc[mi][ni][r] + bias);
        }
      }
    }
  } else {
    bf16* Out = (z == 0) ? Qh : Kh;
    const float scale = (z == 0) ? 0.125f : 1.0f;
#pragma unroll
    for (int ni = 0; ni < 4; ++ni) {
      const int n = n0 + rn + ni * 16 + colx;
      const float bias = Bv[n];
#pragma unroll
      for (int mi = 0; mi < 4; ++mi) {
#pragma unroll
        for (int r = 0; r < 4; ++r) {
          const int m = m0 + rm + mi * 16 + quad * 4 + r;
          const float v = (acc[mi][ni][r] + bias) * scale;
          const int b = m >> 11, l = m & 2047, hh = n >> 6, d = n & 63;
          Out[((size_t)(b * NH + hh) * SEQ + l) * HD + d] = (bf16)v;
        }
      }
    }
  }
}

// ---------------------------------------------------------------------------
// Output projection: out = At[4096,1024] @ Wo^T + bo (fp32 store).
// Same XCD remap + single-buffer structure.
// ---------------------------------------------------------------------------
__global__ __launch_bounds__(256, 4) void proj_out(
    const bf16* __restrict__ At, const bf16* __restrict__ Wob,
    const float* __restrict__ bo, float* __restrict__ Out)
{
  __shared__ __align__(16) bf16 sA[128 * 64];
  __shared__ __align__(16) bf16 sB[128 * 64];

  const int o = (int)blockIdx.x + 8 * (int)blockIdx.y;
  const int m0 = ((o & 7) * 4 + ((o >> 3) & 3)) * 128;
  const int n0 = (o >> 5) * 128;

  const int tid  = threadIdx.x;
  const int lane = tid & 63;
  const int wv   = tid >> 6;
  const int quad = lane >> 4;
  const int colx = lane & 15;
  const int rm = (wv >> 1) * 64;
  const int rn = (wv & 1) * 64;

  f32x4 acc[4][4];
#pragma unroll
  for (int mi = 0; mi < 4; ++mi)
#pragma unroll
    for (int ni = 0; ni < 4; ++ni) {
      f32x4 zz = {0.f, 0.f, 0.f, 0.f};
      acc[mi][ni] = zz;
    }

  for (int kt = 0; kt < 16; ++kt) {
    const int k0 = kt * 64;
    __syncthreads();
#pragma unroll
    for (int i = 0; i < 4; ++i) {
      const int f = i * 256 + tid;
      const int row = f >> 3;
      const int cc = (f & 7) ^ (row & 7);
      glds16(At  + (size_t)(m0 + row) * DM + k0 + cc * 8, sA + f * 8);
      glds16(Wob + (size_t)(n0 + row) * DM + k0 + cc * 8, sB + f * 8);
    }
    __syncthreads();

    bf16x8 af[4][2], bfr[4][2];
#pragma unroll
    for (int t4 = 0; t4 < 4; ++t4) {
#pragma unroll
      for (int ks = 0; ks < 2; ++ks) {
        const int ra = rm + t4 * 16 + colx;
        af[t4][ks] = *(const bf16x8*)(sA + ra * 64 + (((ks * 4 + quad) ^ (ra & 7)) * 8));
        const int rb = rn + t4 * 16 + colx;
        bfr[t4][ks] = *(const bf16x8*)(sB + rb * 64 + (((ks * 4 + quad) ^ (rb & 7)) * 8));
      }
    }
#pragma unroll
    for (int mi = 0; mi < 4; ++mi)
#pragma unroll
      for (int ni = 0; ni < 4; ++ni) {
        acc[mi][ni] = __builtin_amdgcn_mfma_f32_16x16x32_bf16(af[mi][0], bfr[ni][0], acc[mi][ni], 0, 0, 0);
        acc[mi][ni] = __builtin_amdgcn_mfma_f32_16x16x32_bf16(af[mi][1], bfr[ni][1], acc[mi][ni], 0, 0, 0);
      }
  }

#pragma unroll
  for (int ni = 0; ni < 4; ++ni) {
    const int n = n0 + rn + ni * 16 + colx;
    const float bias = bo[n];
#pragma unroll
    for (int mi = 0; mi < 4; ++mi) {
#pragma unroll
      for (int r = 0; r < 4; ++r) {
        const int m = m0 + rm + mi * 16 + quad * 4 + r;
        Out[(size_t)m * DM + n] = acc[mi][ni][r] + bias;
      }
    }
  }
}

// ---------------------------------------------------------------------------
// Flash attention (unchanged from R6 — verified, 0 bank conflicts).
// ---------------------------------------------------------------------------
__global__ __launch_bounds__(256, 2) void attn_kernel(
    const bf16* __restrict__ Qh, const bf16* __restrict__ Kh, const bf16* __restrict__ Vt,
    const int* __restrict__ mask, bf16* __restrict__ At)
{
  __shared__ __align__(16) bf16 sK[128 * 64];
  __shared__ __align__(16) bf16 sVt[80 * 128];
  __shared__ __align__(16) bf16 sP[4][32 * 128];

  const int tid  = threadIdx.x;
  const int lane = tid & 63;
  const int wv   = tid >> 6;
  const int quad = lane >> 4;
  const int colx = lane & 15;
  const int bh = blockIdx.y;
  const int b  = bh >> 4;
  const int h  = bh & 15;
  const int q0 = blockIdx.x * 128;
  const size_t base  = (size_t)bh * SEQ * HD;
  const size_t baseV = (size_t)bh * HD * SEQ;

  {
    const int row = 64 + (tid >> 4);
    const float val = (row == 64) ? 1.0f : 0.0f;
    bf16x8 vv;
#pragma unroll
    for (int j = 0; j < 8; ++j) vv[j] = (bf16)val;
    *(bf16x8*)(sVt + row * 128 + (tid & 15) * 8) = vv;
  }

  bf16x8 qf[2][2];
#pragma unroll
  for (int half = 0; half < 2; ++half) {
    const int qrow = q0 + wv * 32 + half * 16 + colx;
    qf[half][0] = *(const bf16x8*)(Qh + base + (size_t)qrow * HD + quad * 8);
    qf[half][1] = *(const bf16x8*)(Qh + base + (size_t)qrow * HD + 32 + quad * 8);
  }

  f32x4 o[2][5];
#pragma unroll
  for (int half = 0; half < 2; ++half)
#pragma unroll
    for (int dt = 0; dt < 5; ++dt) {
      f32x4 zz = {0.f, 0.f, 0.f, 0.f};
      o[half][dt] = zz;
    }
  bf16* sPw = &sP[wv][0];

  for (int kc = 0; kc < 16; ++kc) {
    const int key0 = kc * 128;
    __syncthreads();
#pragma unroll
    for (int i = 0; i < 4; ++i) {
      const int f = i * 256 + tid;
      const int kr = f >> 3;
      const int ck = (f & 7) ^ (kr & 7);
      glds16(Kh + base + (size_t)(key0 + kr) * HD + ck * 8, sK + f * 8);
      const int dr = f >> 4;
      const int cv = (f & 15) ^ (dr & 15);
      glds16(Vt + baseV + (size_t)dr * SEQ + key0 + cv * 8, sVt + f * 8);
    }
    float mreg[8];
#pragma unroll
    for (int nt = 0; nt < 8; ++nt)
      mreg[nt] = (mask[b * SEQ + key0 + nt * 16 + colx] ? -1e30f : 0.0f) - 16.0f;
    __syncthreads();

#pragma unroll
    for (int half = 0; half < 2; ++half) {
      f32x4 s8[8];
#pragma unroll
      for (int nt = 0; nt < 8; ++nt) {
        f32x4 s = {0.f, 0.f, 0.f, 0.f};
        const int krow = nt * 16 + colx;
#pragma unroll
        for (int ks = 0; ks < 2; ++ks) {
          const bf16x8 kf = *(const bf16x8*)(sK + krow * 64 + (((ks * 4 + quad) ^ (krow & 7)) * 8));
          s = __builtin_amdgcn_mfma_f32_16x16x32_bf16(qf[half][ks], kf, s, 0, 0, 0);
        }
        s8[nt] = s;
      }
#pragma unroll
      for (int r = 0; r < 4; ++r) {
        bf16x8 pk;
#pragma unroll
        for (int nt = 0; nt < 8; ++nt)
          pk[nt] = (bf16)__expf(s8[nt][r] + mreg[nt]);
        const int row = half * 16 + quad * 4 + r;
        *(bf16x8*)(sPw + row * 128 + ((colx ^ (row & 15)) * 8)) = pk;
      }
    }

#pragma unroll
    for (int ks = 0; ks < 4; ++ks) {
      const int ch = ((ks * 4 + quad) ^ colx) * 8;
      const bf16x8 pf0 = *(const bf16x8*)(sPw + colx * 128 + ch);
      const bf16x8 pf1 = *(const bf16x8*)(sPw + (16 + colx) * 128 + ch);
#pragma unroll
      for (int dt = 0; dt < 5; ++dt) {
        const int drow = (dt < 4) ? (dt * 16 + colx) : (64 + colx);
        const bf16x8 vf = *(const bf16x8*)(sVt + drow * 128 + ch);
        o[0][dt] = __builtin_amdgcn_mfma_f32_16x16x32_bf16(pf0, vf, o[0][dt], 0, 0, 0);
        o[1][dt] = __builtin_amdgcn_mfma_f32_16x16x32_bf16(pf1, vf, o[1][dt], 0, 0, 0);
      }
    }
  }

#pragma unroll
  for (int half = 0; half < 2; ++half) {
#pragma unroll
    for (int r = 0; r < 4; ++r) {
      const float lsum = __shfl(o[half][4][r], (lane & 48));
      const float inv = 1.0f / lsum;
      const int q = q0 + wv * 32 + half * 16 + quad * 4 + r;
#pragma unroll
      for (int dt = 0; dt < 4; ++dt) {
        At[((size_t)(b * SEQ + q)) * DM + h * HD + dt * 16 + colx] =
            (bf16)(o[half][dt][r] * inv);
      }
    }
  }
}

extern "C" void kernel_launch(void* const* d_in, const int* in_sizes, int n_in,
                              void* d_out, int out_size, void* d_ws, size_t ws_size,
                              hipStream_t stream) {
  (void)in_sizes; (void)n_in; (void)out_size; (void)ws_size;
  const float* q    = (const float*)d_in[0];
  const float* k    = (const float*)d_in[1];
  const float* v    = (const float*)d_in[2];
  const int*   mask = (const int*)d_in[3];
  const float* Wq   = (const float*)d_in[4];
  const float* bq   = (const float*)d_in[5];
  const float* Wk   = (const float*)d_in[6];
  const float* bk   = (const float*)d_in[7];
  const float* Wv   = (const float*)d_in[8];
  const float* bv   = (const float*)d_in[9];
  const float* Wo   = (const float*)d_in[10];
  const float* bo   = (const float*)d_in[11];
  float* out = (float*)d_out;

  const size_t T = (size_t)MROWS * DM;   // 4,194,304
  const size_t WT = (size_t)DM * DM;     // 1,048,576
  bf16* ws  = (bf16*)d_ws;
  bf16* qb  = ws;             // later reused as At (qb dead after proj_qkv)
  bf16* kb  = qb + T;
  bf16* vb  = kb + T;
  bf16* Wqb = vb + T;
  bf16* Wkb = Wqb + WT;
  bf16* Wvb = Wkb + WT;
  bf16* Wob = Wvb + WT;
  bf16* Qh  = Wob + WT;
  bf16* Kh  = Qh + T;
  bf16* Vt  = Kh + T;
  bf16* At  = qb;             // alias: safe, qb consumed before attn writes At

  dim3 blk(256);
  conv_all<<<8192, blk, 0, stream>>>(q, k, v, Wq, Wk, Wv, Wo,
                                     qb, kb, vb, Wqb, Wkb, Wvb, Wob);
  proj_qkv<<<dim3(8, 32, 3), blk, 0, stream>>>(qb, kb, vb, Wqb, Wkb, Wvb,
                                               bq, bk, bv, Qh, Kh, Vt);
  attn_kernel<<<dim3(16, 32), blk, 0, stream>>>(Qh, Kh, Vt, mask, At);
  proj_out<<<dim3(8, 32), blk, 0, stream>>>(At, Wob, bo, out);
}